// Round 7
// baseline (268.413 us; speedup 1.0000x reference)
//
#include <hip/hip_runtime.h>
#include <hip/hip_bf16.h>

typedef short bf16x8 __attribute__((ext_vector_type(8)));
typedef float f32x4 __attribute__((ext_vector_type(4)));
typedef unsigned int uint2v __attribute__((ext_vector_type(2)));

__device__ __forceinline__ float bf2f(ushort u) {
    union { unsigned int i; float f; } v; v.i = ((unsigned int)u) << 16; return v.f;
}
__device__ __forceinline__ ushort f2bf(float f) {
    union { float f; unsigned int i; } v; v.f = f;
    unsigned int x = v.i;
    x += 0x7fffu + ((x >> 16) & 1u);  // RNE (finite values only)
    return (ushort)(x >> 16);
}

#define MFMA(a, b, c) __builtin_amdgcn_mfma_f32_16x16x32_bf16(a, b, c, 0, 0, 0)

// fine-grained barrier: wait for all but the newest N vmem ops, then s_barrier.
#define WAIT_BARRIER(N) asm volatile("s_waitcnt vmcnt(" #N ")\n\ts_barrier" ::: "memory")

// async global->LDS, 16B/lane; LDS dest = wave-uniform base + lane*16
__device__ __forceinline__ void gld_lds16(const ushort* g, ushort* l) {
    __builtin_amdgcn_global_load_lds(
        (const __attribute__((address_space(1))) unsigned int*)g,
        (__attribute__((address_space(3))) unsigned int*)l, 16, 0, 0);
}

// ws layout (ushort elems)
#define WS_XT 0
#define WS_XS 4194304
#define WS_WQ 8388608
#define WS_WK 9437184
#define WS_WV 10485760
#define WS_WO 11534336
#define WS_QH 12582912
#define WS_KH 16777216
#define WS_VT 20971520
#define WS_AO 0   // reuses XT region (XT dead after qkv_gemm)

// ---------------- cast: fp32 -> bf16 into ws ----------------
// seg 2 (Wq) folds the softmax scale log2(e)/sqrt(Dh) into the weights, so
// flash_attn loads Q raw (no per-element repack) and Q is single-rounded.
__global__ __launch_bounds__(256) void cast_bf16(
    const float* __restrict__ s0, const float* __restrict__ s1,
    const float* __restrict__ s2, const float* __restrict__ s3,
    const float* __restrict__ s4, const float* __restrict__ s5,
    ushort* __restrict__ ws)
{
    const int seg = blockIdx.y;
    const float* src = seg == 0 ? s0 : seg == 1 ? s1 : seg == 2 ? s2
                     : seg == 3 ? s3 : seg == 4 ? s4 : s5;
    const size_t off = seg == 0 ? WS_XT : seg == 1 ? WS_XS : seg == 2 ? WS_WQ
                     : seg == 3 ? WS_WK : seg == 4 ? WS_WV : (size_t)WS_WO;
    const int n4 = (seg < 2) ? 1048576 : 262144;  // float4 count
    const float scl = (seg == 2) ? 0.18033688f : 1.0f;
    ushort* d = ws + off;
    for (int i = blockIdx.x * 256 + threadIdx.x; i < n4; i += gridDim.x * 256) {
        float4 f = ((const float4*)src)[i];
        ushort4 u;
        u.x = f2bf(f.x * scl); u.y = f2bf(f.y * scl);
        u.z = f2bf(f.z * scl); u.w = f2bf(f.w * scl);
        ((ushort4*)d)[i] = u;
    }
}

// ---------------- qkv GEMM: 128x128 tile, tri-buffer fine-vmcnt --------------
// grid (8, 32, 3): z = 0:Q, 1:K, 2:Vt. All epilogues route through LDS
// for 16B coalesced stores. XCD swizzle: m-tile = id&31 so all 8 n-tiles of
// an A-panel land on one XCD (id%8 == (id&31)%8; z*256 ≡ 0 mod 8, so modes
// 1/2 sharing xs co-locate too) -> A-panel fetched into one L2, not eight.
__global__ __launch_bounds__(256) void gemm128(
    const ushort* __restrict__ xtb, const ushort* __restrict__ xsb,
    const ushort* __restrict__ wqb, const ushort* __restrict__ wkb,
    const ushort* __restrict__ wvb,
    ushort* __restrict__ qh, ushort* __restrict__ kh, ushort* __restrict__ vt)
{
    __shared__ __align__(16) ushort SM[24576];  // A: 3x4096, B: 12288 + 3x4096

    const int mode = blockIdx.z;
    const ushort* Ap = (mode == 0) ? xtb : xsb;
    const ushort* Wp = (mode == 0) ? wqb : (mode == 1 ? wkb : wvb);

    const int tid  = threadIdx.x;
    const int wave = tid >> 6, lane = tid & 63;
    const int quad = lane >> 4, lidx = lane & 15;
    const int wm = wave >> 1, wn = wave & 1;
    const int id = blockIdx.x + 8 * blockIdx.y;   // 0..255, hw-dispatch linear
    const int m0 = (id & 31) * 128, n0 = (id >> 5) * 128;

    const int slr = lane >> 2, scb = lane & 3;
    auto stage = [&](int k0, int bufi) {
        ushort* Asb = SM + bufi * 4096;
        ushort* Bsb = SM + 12288 + bufi * 4096;
#pragma unroll
        for (int i2 = 0; i2 < 2; ++i2) {
            const int i = wave + i2 * 4;
            const int r = i * 16 + slr;
            gld_lds16(Ap + (size_t)(m0 + r) * 1024 + k0 + scb * 8, Asb + i * 512);
            gld_lds16(Wp + (size_t)(n0 + r) * 1024 + k0 + scb * 8, Bsb + i * 512);
        }
    };

    f32x4 acc[4][4] = {};
    stage(0, 0);
    stage(32, 1);

    for (int kt = 0; kt < 32; ++kt) {
        const int cur = kt % 3;
        WAIT_BARRIER(4);
        stage(((kt + 2) & 31) * 32, (kt + 2) % 3);
        const ushort* Asb = SM + cur * 4096;
        const ushort* Bsb = SM + 12288 + cur * 4096;
        bf16x8 af[4], bfr[4];
#pragma unroll
        for (int i = 0; i < 4; ++i) {
            af[i]  = *(const bf16x8*)(Asb + (wm * 64 + i * 16 + lidx) * 32 + quad * 8);
            bfr[i] = *(const bf16x8*)(Bsb + (wn * 64 + i * 16 + lidx) * 32 + quad * 8);
        }
#pragma unroll
        for (int mi = 0; mi < 4; ++mi)
#pragma unroll
            for (int ni = 0; ni < 4; ++ni)
                acc[mi][ni] = MFMA(af[mi], bfr[ni], acc[mi][ni]);
    }
    __syncthreads();  // full drain once: epilogue reuses SM as scratch

    ushort* scr = SM + wave * 4096;  // wave-private 8 KB (64x64 tile)

    if (mode == 2) {
        // Vt: scr[dl][swz(tl)] then coalesced stores along t
#pragma unroll
        for (int mi = 0; mi < 4; ++mi)
#pragma unroll
            for (int ni = 0; ni < 4; ++ni)
#pragma unroll
                for (int r = 0; r < 4; ++r) {
                    const int dl = ni * 16 + lidx;
                    const int tl = mi * 16 + quad * 4 + r;
                    const int col = (((tl >> 3) ^ (dl & 7)) << 3) | (tl & 7);
                    scr[dl * 64 + col] = f2bf(acc[mi][ni][r]);
                }
        asm volatile("s_waitcnt lgkmcnt(0)" ::: "memory");
        const int hh = (n0 + wn * 64) >> 6;
        const int bb = m0 >> 11;
        const int t0 = (m0 + wm * 64) & 2047;
        ushort* Vtp = vt + (size_t)(bb * 16 + hh) * 64 * 2048;
#pragma unroll
        for (int ii = 0; ii < 8; ++ii) {
            const int dl = ii * 8 + (lane >> 3);
            const int tb = lane & 7;
            uint4 vd = *(const uint4*)(scr + dl * 64 + ((tb ^ (dl & 7)) << 3));
            *(uint4*)(Vtp + (size_t)dl * 2048 + t0 + tb * 8) = vd;
        }
        return;
    }

    // Q/K: scr[tl][swz(dl)] then coalesced 16B stores along d (one head/wave)
#pragma unroll
    for (int mi = 0; mi < 4; ++mi)
#pragma unroll
        for (int ni = 0; ni < 4; ++ni)
#pragma unroll
            for (int r = 0; r < 4; ++r) {
                const int tl = mi * 16 + quad * 4 + r;
                const int dl = ni * 16 + lidx;
                const int col = (((dl >> 3) ^ (tl & 7)) << 3) | (dl & 7);
                scr[tl * 64 + col] = f2bf(acc[mi][ni][r]);
            }
    asm volatile("s_waitcnt lgkmcnt(0)" ::: "memory");
    {
        ushort* dst = (mode == 0) ? qh : kh;
        const int hh = (n0 + wn * 64) >> 6;
        const int bb = m0 >> 11;
        const int tbase = (m0 + wm * 64) & 2047;
        ushort* Hp = dst + (size_t)(bb * 16 + hh) * 2048 * 64;
#pragma unroll
        for (int ii = 0; ii < 8; ++ii) {
            const int tl = ii * 8 + (lane >> 3);
            const int c  = lane & 7;
            uint4 vd = *(const uint4*)(scr + tl * 64 + ((c ^ (tl & 7)) << 3));
            *(uint4*)(Hp + (size_t)(tbase + tl) * 64 + c * 8) = vd;
        }
    }
}

// ---------------- out GEMM: 128x64 tile, tri-buffer fine-vmcnt ---------------
// XCD swizzle: m-tile = id&31 localizes the AO panel per XCD.
__global__ __launch_bounds__(256) void gemm_out(
    const ushort* __restrict__ aob, const ushort* __restrict__ wob,
    const float* __restrict__ bias, float* __restrict__ outf)
{
    __shared__ __align__(16) ushort SM[18432];

    const int tid  = threadIdx.x;
    const int wave = tid >> 6, lane = tid & 63;
    const int quad = lane >> 4, lidx = lane & 15;
    const int id = blockIdx.x + 16 * blockIdx.y;  // 0..511
    const int m0 = (id & 31) * 128, n0 = (id >> 5) * 64;

    const int slr = lane >> 2, scb = lane & 3;
    auto stage = [&](int k0, int bufi) {
        ushort* Asb = SM + bufi * 4096;
        ushort* Bsb = SM + 12288 + bufi * 2048;
#pragma unroll
        for (int i2 = 0; i2 < 2; ++i2) {
            const int i = wave * 2 + i2;
            gld_lds16(aob + (size_t)(m0 + i * 16 + slr) * 1024 + k0 + scb * 8,
                      Asb + i * 512);
        }
        gld_lds16(wob + (size_t)(n0 + wave * 16 + slr) * 1024 + k0 + scb * 8,
                  Bsb + wave * 512);
    };

    f32x4 acc[2][4] = {};
    stage(0, 0);
    stage(32, 1);

    for (int kt = 0; kt < 32; ++kt) {
        const int cur = kt % 3;
        WAIT_BARRIER(3);
        stage(((kt + 2) & 31) * 32, (kt + 2) % 3);
        const ushort* Asb = SM + cur * 4096;
        const ushort* Bsb = SM + 12288 + cur * 2048;
        bf16x8 af[2], bfr[4];
#pragma unroll
        for (int i = 0; i < 2; ++i)
            af[i] = *(const bf16x8*)(Asb + (wave * 32 + i * 16 + lidx) * 32 + quad * 8);
#pragma unroll
        for (int i = 0; i < 4; ++i)
            bfr[i] = *(const bf16x8*)(Bsb + (i * 16 + lidx) * 32 + quad * 8);
#pragma unroll
        for (int mi = 0; mi < 2; ++mi)
#pragma unroll
            for (int ni = 0; ni < 4; ++ni)
                acc[mi][ni] = MFMA(af[mi], bfr[ni], acc[mi][ni]);
    }

#pragma unroll
    for (int mi = 0; mi < 2; ++mi)
#pragma unroll
        for (int ni = 0; ni < 4; ++ni)
#pragma unroll
            for (int r = 0; r < 4; ++r) {
                const int m = m0 + wave * 32 + mi * 16 + quad * 4 + r;
                const int n = n0 + ni * 16 + lidx;
                outf[(size_t)m * 1024 + n] = acc[mi][ni][r] + bias[n];
            }
}

// ---------------- flash_attn v11: V direct from global (L1-served) ----------
// v10 model: 86% of flash = DS pipe (K 96 + V 96 + stage 16 cyc/wave-iter);
// all 8 waves re-read the SAME 8KB V tile from LDS. m169 lesson: when the
// tile is cache-resident, staging is overhead. V-frags now load straight
// from Vt global (16 rows x 4KB stride, 64B/row contiguous): wave 0 misses
// to L2, waves 1-7 hit L1 (8KB << 32KB L1). V moves to the TA/L1 pipe which
// runs PARALLEL to DS: max(DS 104, L1 ~144) < 208. K stays LDS-staged
// (tri-buffer, 1 gld_lds/thread, WAIT_BARRIER(1)); V-loads issue before
// QK^T so HBM/L2 latency hides under QK+softmax; vmcnt(1) before PV keeps
// stage(j+2) in flight. LDS 48->24KB.
__global__ __launch_bounds__(512, 6) void flash_attn(
    const ushort* __restrict__ Qh, const ushort* __restrict__ Kh,
    const ushort* __restrict__ Vt, ushort* __restrict__ AO)
{
    __shared__ __align__(16) ushort Kb[3][4096];

    const int tid  = threadIdx.x;
    const int wave = tid >> 6, lane = tid & 63;
    const int quad = lane >> 4, lidx = lane & 15;
    const int bh = blockIdx.y;
    const int b = bh >> 4, h = bh & 15;
    const int qbase = blockIdx.x * 128 + wave * 16;

    const ushort* Qp = Qh + (size_t)bh * 2048 * 64;
    const ushort* Kp = Kh + (size_t)bh * 2048 * 64;
    const ushort* Vp = Vt + (size_t)bh * 64 * 2048;

    // Q as B-operand fragments (pre-scaled at cast): raw 16B loads
    bf16x8 q0, q1;
    {
        const ushort* qr = Qp + (size_t)(qbase + lidx) * 64 + quad * 8;
        q0 = *(const bf16x8*)qr;
        q1 = *(const bf16x8*)(qr + 32);
    }

    // V fragment base pointers: row d = n0*16+lidx, col chunk quad*8 (16B)
    const ushort* vb[4];
#pragma unroll
    for (int n0 = 0; n0 < 4; ++n0)
        vb[n0] = Vp + (size_t)(n0 * 16 + lidx) * 2048 + quad * 8;

    // stage 64x64 K tile (row-swizzled); 512 threads x 16B = 8KB, one issue
    auto stage = [&](int s0, int bufi) {
        const int slot = wave * 64 + lane;
        const int r  = slot >> 3;
        const int bb = slot & 7;
        const int gb = bb ^ (r & 7);
        gld_lds16(Kp + (size_t)(s0 + r) * 64 + gb * 8, &Kb[bufi][wave * 512]);
    };

    // permlane32_swap then permlane16_swap: (x,y) value-quad layout
    // (x0,x1,x2,x3),(y0,y1,y2,y3) -> (x0,x2,y0,y2),(x1,x3,y1,y3)
    auto swap2 = [&](uint& x, uint& y) {
        uint2v r1 = __builtin_amdgcn_permlane32_swap(x, y, false, false);
        uint2v r2 = __builtin_amdgcn_permlane16_swap(r1[0], r1[1], false, false);
        x = r2[0]; y = r2[1];
    };

    float lsum = 0.f;
    f32x4 o[4] = {};

    stage(0, 0);
    stage(64, 1);

    for (int j = 0; j < 32; ++j) {
        const int cur = j % 3;
        // K tile j staged (only stage(j+1) may still be in flight), sync
        WAIT_BARRIER(1);

        // issue V loads for tile j early: latency hides under QK + softmax
        const int s0 = j * 64;
        bf16x8 v0[4], v1[4];
#pragma unroll
        for (int n0 = 0; n0 < 4; ++n0) {
            v0[n0] = *(const bf16x8*)(vb[n0] + s0);
            v1[n0] = *(const bf16x8*)(vb[n0] + s0 + 32);
        }

        stage(((j + 2) & 31) * 64, (j + 2) % 3);

        // QK^T swapped: s[n0][r] = S[q = lidx][k = n0*16 + quad*4 + r]
        f32x4 s[4] = {};
#pragma unroll
        for (int n0 = 0; n0 < 4; ++n0) {
            const int row = n0 * 16 + lidx;
            bf16x8 kA = *(const bf16x8*)&Kb[cur][row * 64 + ((quad ^ (row & 7)) * 8)];
            bf16x8 kB = *(const bf16x8*)&Kb[cur][row * 64 + (((4 + quad) ^ (row & 7)) * 8)];
            s[n0] = MFMA(kA, q0, s[n0]);
            s[n0] = MFMA(kB, q1, s[n0]);
        }

        // softmax numerator: exp2 + pack; W[n0][h] = bf16 pair k=(16n0+4q+2h,+1)
        uint W[4][2];
#pragma unroll
        for (int n0 = 0; n0 < 4; ++n0) {
            float p0 = __builtin_amdgcn_exp2f(s[n0][0]);
            float p1 = __builtin_amdgcn_exp2f(s[n0][1]);
            float p2 = __builtin_amdgcn_exp2f(s[n0][2]);
            float p3 = __builtin_amdgcn_exp2f(s[n0][3]);
            lsum += (p0 + p1) + (p2 + p3);
            asm("v_cvt_pk_bf16_f32 %0, %1, %2" : "=v"(W[n0][0]) : "v"(p0), "v"(p1));
            asm("v_cvt_pk_bf16_f32 %0, %1, %2" : "=v"(W[n0][1]) : "v"(p2), "v"(p3));
        }

        // cross-quad redistribution in-register (no P LDS round-trip)
        uint aw0 = W[0][0], aw2 = W[1][0]; swap2(aw0, aw2);
        uint aw1 = W[0][1], aw3 = W[1][1]; swap2(aw1, aw3);
        uint bw0 = W[2][0], bw2 = W[3][0]; swap2(bw0, bw2);
        uint bw1 = W[2][1], bw3 = W[3][1]; swap2(bw1, bw3);
        union { uint u[4]; bf16x8 v; } PA, PB;
        PA.u[0] = aw0; PA.u[1] = aw1; PA.u[2] = aw2; PA.u[3] = aw3;
        PB.u[0] = bw0; PB.u[1] = bw1; PB.u[2] = bw2; PB.u[3] = bw3;

        // V loads done (stage(j+2) stays in flight), then PV
        asm volatile("s_waitcnt vmcnt(1)" ::: "memory");
#pragma unroll
        for (int n0 = 0; n0 < 4; ++n0) {
            o[n0] = MFMA(PA.v, v0[n0], o[n0]);
            o[n0] = MFMA(PB.v, v1[n0], o[n0]);
        }
        // no end-of-iter barrier: next iter's WAIT_BARRIER(1) provides the
        // sync; tri-buffering guarantees stage(j+2) overwrites a K buffer
        // last read at iter j-1 (pre-barrier).
    }

    // row sums: lane owns q = lidx; reduce partial sums over the 4 quads
    {
        float v = lsum;
        v += __shfl_xor(v, 16);
        v += __shfl_xor(v, 32);
        lsum = v;
    }
    float rs[4];
#pragma unroll
    for (int r = 0; r < 4; ++r)
        rs[r] = 1.0f / __shfl(lsum, quad * 4 + r);

#pragma unroll
    for (int n0 = 0; n0 < 4; ++n0)
#pragma unroll
        for (int r = 0; r < 4; ++r) {
            const int tt = qbase + quad * 4 + r;
            const int d  = n0 * 16 + lidx;
            AO[(size_t)(b * 2048 + tt) * 1024 + h * 64 + d] =
                f2bf(o[n0][r] * rs[r]);
        }
}

extern "C" void kernel_launch(void* const* d_in, const int* in_sizes, int n_in,
                              void* d_out, int out_size, void* d_ws, size_t ws_size,
                              hipStream_t stream) {
    const float* xt = (const float*)d_in[0];
    const float* xs = (const float*)d_in[1];
    const float* Wq = (const float*)d_in[2];
    const float* Wk = (const float*)d_in[3];
    const float* Wv = (const float*)d_in[4];
    const float* Wo = (const float*)d_in[5];
    const float* bo = (const float*)d_in[6];
    float* out = (float*)d_out;

    ushort* ws = (ushort*)d_ws;

    cast_bf16<<<dim3(1024, 6, 1), 256, 0, stream>>>(xt, xs, Wq, Wk, Wv, Wo, ws);

    gemm128<<<dim3(8, 32, 3), 256, 0, stream>>>(
        ws + WS_XT, ws + WS_XS, ws + WS_WQ, ws + WS_WK, ws + WS_WV,
        ws + WS_QH, ws + WS_KH, ws + WS_VT);

    flash_attn<<<dim3(16, 32, 1), 512, 0, stream>>>(
        ws + WS_QH, ws + WS_KH, ws + WS_VT, ws + WS_AO);

    gemm_out<<<dim3(16, 32, 1), 256, 0, stream>>>(
        ws + WS_AO, ws + WS_WO, bo, out);
}

// Round 8
// 198.351 us; speedup vs baseline: 1.3532x; 1.3532x over previous
//
#include <hip/hip_runtime.h>
#include <hip/hip_bf16.h>

typedef short bf16x8 __attribute__((ext_vector_type(8)));
typedef float f32x4 __attribute__((ext_vector_type(4)));
typedef unsigned int uint2v __attribute__((ext_vector_type(2)));

__device__ __forceinline__ float bf2f(ushort u) {
    union { unsigned int i; float f; } v; v.i = ((unsigned int)u) << 16; return v.f;
}
__device__ __forceinline__ ushort f2bf(float f) {
    union { float f; unsigned int i; } v; v.f = f;
    unsigned int x = v.i;
    x += 0x7fffu + ((x >> 16) & 1u);  // RNE (finite values only)
    return (ushort)(x >> 16);
}

#define MFMA(a, b, c) __builtin_amdgcn_mfma_f32_16x16x32_bf16(a, b, c, 0, 0, 0)

// fine-grained barrier: wait for all but the newest N vmem ops, then s_barrier.
#define WAIT_BARRIER(N) asm volatile("s_waitcnt vmcnt(" #N ")\n\ts_barrier" ::: "memory")

// async global->LDS, 16B/lane; LDS dest = wave-uniform base + lane*16
__device__ __forceinline__ void gld_lds16(const ushort* g, ushort* l) {
    __builtin_amdgcn_global_load_lds(
        (const __attribute__((address_space(1))) unsigned int*)g,
        (__attribute__((address_space(3))) unsigned int*)l, 16, 0, 0);
}

// ws layout (ushort elems)
#define WS_XT 0
#define WS_XS 4194304
#define WS_WQ 8388608
#define WS_WK 9437184
#define WS_WV 10485760
#define WS_WO 11534336
#define WS_QH 12582912
#define WS_KH 16777216
#define WS_VT 20971520
#define WS_AO 0   // reuses XT region (XT dead after qkv_gemm)

// ---------------- cast: fp32 -> bf16 into ws ----------------
// seg 2 (Wq) folds the softmax scale log2(e)/sqrt(Dh) into the weights, so
// flash_attn loads Q raw (no per-element repack) and Q is single-rounded.
__global__ __launch_bounds__(256) void cast_bf16(
    const float* __restrict__ s0, const float* __restrict__ s1,
    const float* __restrict__ s2, const float* __restrict__ s3,
    const float* __restrict__ s4, const float* __restrict__ s5,
    ushort* __restrict__ ws)
{
    const int seg = blockIdx.y;
    const float* src = seg == 0 ? s0 : seg == 1 ? s1 : seg == 2 ? s2
                     : seg == 3 ? s3 : seg == 4 ? s4 : s5;
    const size_t off = seg == 0 ? WS_XT : seg == 1 ? WS_XS : seg == 2 ? WS_WQ
                     : seg == 3 ? WS_WK : seg == 4 ? WS_WV : (size_t)WS_WO;
    const int n4 = (seg < 2) ? 1048576 : 262144;  // float4 count
    const float scl = (seg == 2) ? 0.18033688f : 1.0f;
    ushort* d = ws + off;
    for (int i = blockIdx.x * 256 + threadIdx.x; i < n4; i += gridDim.x * 256) {
        float4 f = ((const float4*)src)[i];
        ushort4 u;
        u.x = f2bf(f.x * scl); u.y = f2bf(f.y * scl);
        u.z = f2bf(f.z * scl); u.w = f2bf(f.w * scl);
        ((ushort4*)d)[i] = u;
    }
}

// ---------------- qkv GEMM v12: Q mode + FUSED K/Vt mode ---------------------
// grid (8, 32, 2): z=0: Q (A=xt, B=Wq). z=1: fused K+Vt (A=xs staged ONCE,
// A-frags read ONCE per kt and fed to both Wk and Wv MFMAs): 12 ds_reads per
// 32 MFMA vs 16 per 32 when split -> -25% DS frag traffic + A fetched once.
// XCD swizzle: m-tile = id&31 so all 8 n-tiles of an A-panel land on one XCD.
// LDS: A 3x8KB | Bk 3x8KB | Bv 3x8KB = 72KB (z=0 uses A+Bk regions only).
__global__ __launch_bounds__(256) void gemm128(
    const ushort* __restrict__ xtb, const ushort* __restrict__ xsb,
    const ushort* __restrict__ wqb, const ushort* __restrict__ wkb,
    const ushort* __restrict__ wvb,
    ushort* __restrict__ qh, ushort* __restrict__ kh, ushort* __restrict__ vt)
{
    __shared__ __align__(16) ushort SM[36864];  // A@0, Bk@12288, Bv@24576

    const int mode = blockIdx.z;                  // 0: Q, 1: K+Vt fused
    const ushort* Ap = mode ? xsb : xtb;
    const ushort* Bkp = mode ? wkb : wqb;

    const int tid  = threadIdx.x;
    const int wave = tid >> 6, lane = tid & 63;
    const int quad = lane >> 4, lidx = lane & 15;
    const int wm = wave >> 1, wn = wave & 1;
    const int id = blockIdx.x + 8 * blockIdx.y;   // 0..255, hw-dispatch linear
    const int m0 = (id & 31) * 128, n0 = (id >> 5) * 128;

    const int slr = lane >> 2, scb = lane & 3;
    auto stage = [&](int k0, int bufi) {
        ushort* Asb = SM + bufi * 4096;
        ushort* Bksb = SM + 12288 + bufi * 4096;
        ushort* Bvsb = SM + 24576 + bufi * 4096;
#pragma unroll
        for (int i2 = 0; i2 < 2; ++i2) {
            const int i = wave + i2 * 4;
            const int r = i * 16 + slr;
            gld_lds16(Ap + (size_t)(m0 + r) * 1024 + k0 + scb * 8, Asb + i * 512);
            gld_lds16(Bkp + (size_t)(n0 + r) * 1024 + k0 + scb * 8, Bksb + i * 512);
            if (mode)
                gld_lds16(wvb + (size_t)(n0 + r) * 1024 + k0 + scb * 8,
                          Bvsb + i * 512);
        }
    };

    f32x4 aK[4][4] = {};
    f32x4 aV[4][4] = {};
    stage(0, 0);
    stage(32, 1);

    for (int kt = 0; kt < 32; ++kt) {
        const int cur = kt % 3;
        if (mode) { WAIT_BARRIER(6); } else { WAIT_BARRIER(4); }
        stage(((kt + 2) & 31) * 32, (kt + 2) % 3);
        const ushort* Asb = SM + cur * 4096;
        const ushort* Bksb = SM + 12288 + cur * 4096;
        const ushort* Bvsb = SM + 24576 + cur * 4096;
        bf16x8 af[4], bk[4];
#pragma unroll
        for (int i = 0; i < 4; ++i) {
            af[i] = *(const bf16x8*)(Asb + (wm * 64 + i * 16 + lidx) * 32 + quad * 8);
            bk[i] = *(const bf16x8*)(Bksb + (wn * 64 + i * 16 + lidx) * 32 + quad * 8);
        }
#pragma unroll
        for (int mi = 0; mi < 4; ++mi)
#pragma unroll
            for (int ni = 0; ni < 4; ++ni)
                aK[mi][ni] = MFMA(af[mi], bk[ni], aK[mi][ni]);
        if (mode) {
            bf16x8 bv[4];
#pragma unroll
            for (int i = 0; i < 4; ++i)
                bv[i] = *(const bf16x8*)(Bvsb + (wn * 64 + i * 16 + lidx) * 32 + quad * 8);
#pragma unroll
            for (int mi = 0; mi < 4; ++mi)
#pragma unroll
                for (int ni = 0; ni < 4; ++ni)
                    aV[mi][ni] = MFMA(af[mi], bv[ni], aV[mi][ni]);
        }
    }
    __syncthreads();  // full drain once: epilogue reuses SM as scratch

    ushort* scr = SM + wave * 4096;  // wave-private 8 KB (64x64 tile)
    const int hh = (n0 + wn * 64) >> 6;
    const int bb = m0 >> 11;

    // Q/K epilogue: scr[tl][swz(dl)] then coalesced 16B stores along d
    {
#pragma unroll
        for (int mi = 0; mi < 4; ++mi)
#pragma unroll
            for (int ni = 0; ni < 4; ++ni)
#pragma unroll
                for (int r = 0; r < 4; ++r) {
                    const int tl = mi * 16 + quad * 4 + r;
                    const int dl = ni * 16 + lidx;
                    const int col = (((dl >> 3) ^ (tl & 7)) << 3) | (dl & 7);
                    scr[tl * 64 + col] = f2bf(aK[mi][ni][r]);
                }
        asm volatile("s_waitcnt lgkmcnt(0)" ::: "memory");
        ushort* dst = mode ? kh : qh;
        const int tbase = (m0 + wm * 64) & 2047;
        ushort* Hp = dst + (size_t)(bb * 16 + hh) * 2048 * 64;
#pragma unroll
        for (int ii = 0; ii < 8; ++ii) {
            const int tl = ii * 8 + (lane >> 3);
            const int c  = lane & 7;
            uint4 vd = *(const uint4*)(scr + tl * 64 + ((c ^ (tl & 7)) << 3));
            *(uint4*)(Hp + (size_t)(tbase + tl) * 64 + c * 8) = vd;
        }
    }

    if (!mode) return;

    // Vt epilogue: scr[dl][swz(tl)] then coalesced stores along t
    {
#pragma unroll
        for (int mi = 0; mi < 4; ++mi)
#pragma unroll
            for (int ni = 0; ni < 4; ++ni)
#pragma unroll
                for (int r = 0; r < 4; ++r) {
                    const int dl = ni * 16 + lidx;
                    const int tl = mi * 16 + quad * 4 + r;
                    const int col = (((tl >> 3) ^ (dl & 7)) << 3) | (tl & 7);
                    scr[dl * 64 + col] = f2bf(aV[mi][ni][r]);
                }
        asm volatile("s_waitcnt lgkmcnt(0)" ::: "memory");
        const int t0 = (m0 + wm * 64) & 2047;
        ushort* Vtp = vt + (size_t)(bb * 16 + hh) * 64 * 2048;
#pragma unroll
        for (int ii = 0; ii < 8; ++ii) {
            const int dl = ii * 8 + (lane >> 3);
            const int tb = lane & 7;
            uint4 vd = *(const uint4*)(scr + dl * 64 + ((tb ^ (dl & 7)) << 3));
            *(uint4*)(Vtp + (size_t)dl * 2048 + t0 + tb * 8) = vd;
        }
    }
}

// ---------------- out GEMM: 128x64 tile, tri-buffer fine-vmcnt ---------------
// XCD swizzle: m-tile = id&31 localizes the AO panel per XCD.
__global__ __launch_bounds__(256) void gemm_out(
    const ushort* __restrict__ aob, const ushort* __restrict__ wob,
    const float* __restrict__ bias, float* __restrict__ outf)
{
    __shared__ __align__(16) ushort SM[18432];

    const int tid  = threadIdx.x;
    const int wave = tid >> 6, lane = tid & 63;
    const int quad = lane >> 4, lidx = lane & 15;
    const int id = blockIdx.x + 16 * blockIdx.y;  // 0..511
    const int m0 = (id & 31) * 128, n0 = (id >> 5) * 64;

    const int slr = lane >> 2, scb = lane & 3;
    auto stage = [&](int k0, int bufi) {
        ushort* Asb = SM + bufi * 4096;
        ushort* Bsb = SM + 12288 + bufi * 2048;
#pragma unroll
        for (int i2 = 0; i2 < 2; ++i2) {
            const int i = wave * 2 + i2;
            gld_lds16(aob + (size_t)(m0 + i * 16 + slr) * 1024 + k0 + scb * 8,
                      Asb + i * 512);
        }
        gld_lds16(wob + (size_t)(n0 + wave * 16 + slr) * 1024 + k0 + scb * 8,
                  Bsb + wave * 512);
    };

    f32x4 acc[2][4] = {};
    stage(0, 0);
    stage(32, 1);

    for (int kt = 0; kt < 32; ++kt) {
        const int cur = kt % 3;
        WAIT_BARRIER(3);
        stage(((kt + 2) & 31) * 32, (kt + 2) % 3);
        const ushort* Asb = SM + cur * 4096;
        const ushort* Bsb = SM + 12288 + cur * 2048;
        bf16x8 af[2], bfr[4];
#pragma unroll
        for (int i = 0; i < 2; ++i)
            af[i] = *(const bf16x8*)(Asb + (wave * 32 + i * 16 + lidx) * 32 + quad * 8);
#pragma unroll
        for (int i = 0; i < 4; ++i)
            bfr[i] = *(const bf16x8*)(Bsb + (i * 16 + lidx) * 32 + quad * 8);
#pragma unroll
        for (int mi = 0; mi < 2; ++mi)
#pragma unroll
            for (int ni = 0; ni < 4; ++ni)
                acc[mi][ni] = MFMA(af[mi], bfr[ni], acc[mi][ni]);
    }

#pragma unroll
    for (int mi = 0; mi < 2; ++mi)
#pragma unroll
        for (int ni = 0; ni < 4; ++ni)
#pragma unroll
            for (int r = 0; r < 4; ++r) {
                const int m = m0 + wave * 32 + mi * 16 + quad * 4 + r;
                const int n = n0 + ni * 16 + lidx;
                outf[(size_t)m * 1024 + n] = acc[mi][ni][r] + bias[n];
            }
}

// ---------------- flash_attn v10 (proven 51.5us): exact restore -------------
// v11 post-mortem: V-direct-global scattered 16x64B segments and exposed L2
// latency inside the serial chain (129us, MfmaUtil 10%) -> reverted.
__global__ __launch_bounds__(512, 6) void flash_attn(
    const ushort* __restrict__ Qh, const ushort* __restrict__ Kh,
    const ushort* __restrict__ Vt, ushort* __restrict__ AO)
{
    __shared__ __align__(16) ushort Kb[3][4096];
    __shared__ __align__(16) ushort Vb[3][4096];

    const int tid  = threadIdx.x;
    const int wave = tid >> 6, lane = tid & 63;
    const int quad = lane >> 4, lidx = lane & 15;
    const int bh = blockIdx.y;
    const int b = bh >> 4, h = bh & 15;
    const int qbase = blockIdx.x * 128 + wave * 16;

    const ushort* Qp = Qh + (size_t)bh * 2048 * 64;
    const ushort* Kp = Kh + (size_t)bh * 2048 * 64;
    const ushort* Vp = Vt + (size_t)bh * 64 * 2048;

    // Q as B-operand fragments (pre-scaled at cast): raw 16B loads
    bf16x8 q0, q1;
    {
        const ushort* qr = Qp + (size_t)(qbase + lidx) * 64 + quad * 8;
        q0 = *(const bf16x8*)qr;
        q1 = *(const bf16x8*)(qr + 32);
    }

    // stage 64x64 K tile (row-swizzled) + 64x64 Vt tile (d-swizzled)
    // 512 threads x 16B = 8KB per tile, one issue each
    auto stage = [&](int s0, int bufi) {
        const int slot = wave * 64 + lane;
        const int r  = slot >> 3;
        const int bb = slot & 7;
        const int gb = bb ^ (r & 7);
        gld_lds16(Kp + (size_t)(s0 + r) * 64 + gb * 8, &Kb[bufi][wave * 512]);
        gld_lds16(Vp + (size_t)r * 2048 + s0 + gb * 8, &Vb[bufi][wave * 512]);
    };

    // permlane32_swap then permlane16_swap: (x,y) value-quad layout
    // (x0,x1,x2,x3),(y0,y1,y2,y3) -> (x0,x2,y0,y2),(x1,x3,y1,y3)
    auto swap2 = [&](uint& x, uint& y) {
        uint2v r1 = __builtin_amdgcn_permlane32_swap(x, y, false, false);
        uint2v r2 = __builtin_amdgcn_permlane16_swap(r1[0], r1[1], false, false);
        x = r2[0]; y = r2[1];
    };

    float lsum = 0.f;
    f32x4 o[4] = {};

    stage(0, 0);
    stage(64, 1);

    for (int j = 0; j < 32; ++j) {
        const int cur = j % 3;
        // tile j staged (2 newest stages may still be in flight), sync waves
        WAIT_BARRIER(2);
        stage(((j + 2) & 31) * 64, (j + 2) % 3);

        // QK^T swapped: s[n0][r] = S[q = lidx][k = n0*16 + quad*4 + r]
        f32x4 s[4] = {};
#pragma unroll
        for (int n0 = 0; n0 < 4; ++n0) {
            const int row = n0 * 16 + lidx;
            bf16x8 kA = *(const bf16x8*)&Kb[cur][row * 64 + ((quad ^ (row & 7)) * 8)];
            bf16x8 kB = *(const bf16x8*)&Kb[cur][row * 64 + (((4 + quad) ^ (row & 7)) * 8)];
            s[n0] = MFMA(kA, q0, s[n0]);
            s[n0] = MFMA(kB, q1, s[n0]);
        }

        // hoist V fragment reads: latency hides under the softmax VALU block
        bf16x8 v0[4], v1[4];
#pragma unroll
        for (int n0 = 0; n0 < 4; ++n0) {
            const int d = n0 * 16 + lidx;
            v0[n0] = *(const bf16x8*)&Vb[cur][d * 64 + ((quad ^ (d & 7)) * 8)];
            v1[n0] = *(const bf16x8*)&Vb[cur][d * 64 + (((4 + quad) ^ (d & 7)) * 8)];
        }

        // softmax numerator: exp2 + pack; W[n0][h] = bf16 pair k=(16n0+4q+2h,+1)
        uint W[4][2];
#pragma unroll
        for (int n0 = 0; n0 < 4; ++n0) {
            float p0 = __builtin_amdgcn_exp2f(s[n0][0]);
            float p1 = __builtin_amdgcn_exp2f(s[n0][1]);
            float p2 = __builtin_amdgcn_exp2f(s[n0][2]);
            float p3 = __builtin_amdgcn_exp2f(s[n0][3]);
            lsum += (p0 + p1) + (p2 + p3);
            asm("v_cvt_pk_bf16_f32 %0, %1, %2" : "=v"(W[n0][0]) : "v"(p0), "v"(p1));
            asm("v_cvt_pk_bf16_f32 %0, %1, %2" : "=v"(W[n0][1]) : "v"(p2), "v"(p3));
        }

        // cross-quad redistribution in-register (replaces P LDS round-trip)
        uint aw0 = W[0][0], aw2 = W[1][0]; swap2(aw0, aw2);
        uint aw1 = W[0][1], aw3 = W[1][1]; swap2(aw1, aw3);
        uint bw0 = W[2][0], bw2 = W[3][0]; swap2(bw0, bw2);
        uint bw1 = W[2][1], bw3 = W[3][1]; swap2(bw1, bw3);
        union { uint u[4]; bf16x8 v; } PA, PB;
        PA.u[0] = aw0; PA.u[1] = aw1; PA.u[2] = aw2; PA.u[3] = aw3;
        PB.u[0] = bw0; PB.u[1] = bw1; PB.u[2] = bw2; PB.u[3] = bw3;

#pragma unroll
        for (int n0 = 0; n0 < 4; ++n0) {
            o[n0] = MFMA(PA.v, v0[n0], o[n0]);
            o[n0] = MFMA(PB.v, v1[n0], o[n0]);
        }
        // no end-of-iter barrier: next iter's WAIT_BARRIER(2) provides the
        // sync; tri-buffering guarantees stage(j+2) overwrites a buffer last
        // read at iter j-1 (pre-barrier).
    }

    // row sums: lane owns q = lidx; reduce partial sums over the 4 quads
    {
        float v = lsum;
        v += __shfl_xor(v, 16);
        v += __shfl_xor(v, 32);
        lsum = v;
    }
    float rs[4];
#pragma unroll
    for (int r = 0; r < 4; ++r)
        rs[r] = 1.0f / __shfl(lsum, quad * 4 + r);

#pragma unroll
    for (int n0 = 0; n0 < 4; ++n0)
#pragma unroll
        for (int r = 0; r < 4; ++r) {
            const int tt = qbase + quad * 4 + r;
            const int d  = n0 * 16 + lidx;
            AO[(size_t)(b * 2048 + tt) * 1024 + h * 64 + d] =
                f2bf(o[n0][r] * rs[r]);
        }
}

extern "C" void kernel_launch(void* const* d_in, const int* in_sizes, int n_in,
                              void* d_out, int out_size, void* d_ws, size_t ws_size,
                              hipStream_t stream) {
    const float* xt = (const float*)d_in[0];
    const float* xs = (const float*)d_in[1];
    const float* Wq = (const float*)d_in[2];
    const float* Wk = (const float*)d_in[3];
    const float* Wv = (const float*)d_in[4];
    const float* Wo = (const float*)d_in[5];
    const float* bo = (const float*)d_in[6];
    float* out = (float*)d_out;

    ushort* ws = (ushort*)d_ws;

    cast_bf16<<<dim3(1024, 6, 1), 256, 0, stream>>>(xt, xs, Wq, Wk, Wv, Wo, ws);

    gemm128<<<dim3(8, 32, 2), 256, 0, stream>>>(
        ws + WS_XT, ws + WS_XS, ws + WS_WQ, ws + WS_WK, ws + WS_WV,
        ws + WS_QH, ws + WS_KH, ws + WS_VT);

    flash_attn<<<dim3(16, 32, 1), 512, 0, stream>>>(
        ws + WS_QH, ws + WS_KH, ws + WS_VT, ws + WS_AO);

    gemm_out<<<dim3(16, 32, 1), 256, 0, stream>>>(
        ws + WS_AO, ws + WS_WO, bo, out);
}

// Round 9
// 189.643 us; speedup vs baseline: 1.4154x; 1.0459x over previous
//
#include <hip/hip_runtime.h>
#include <hip/hip_bf16.h>

typedef short bf16x8 __attribute__((ext_vector_type(8)));
typedef float f32x4 __attribute__((ext_vector_type(4)));
typedef unsigned int uint2v __attribute__((ext_vector_type(2)));

__device__ __forceinline__ float bf2f(ushort u) {
    union { unsigned int i; float f; } v; v.i = ((unsigned int)u) << 16; return v.f;
}
__device__ __forceinline__ ushort f2bf(float f) {
    union { float f; unsigned int i; } v; v.f = f;
    unsigned int x = v.i;
    x += 0x7fffu + ((x >> 16) & 1u);  // RNE (finite values only)
    return (ushort)(x >> 16);
}

#define MFMA(a, b, c) __builtin_amdgcn_mfma_f32_16x16x32_bf16(a, b, c, 0, 0, 0)

// fine-grained barrier: wait for all but the newest N vmem ops, then s_barrier.
#define WAIT_BARRIER(N) asm volatile("s_waitcnt vmcnt(" #N ")\n\ts_barrier" ::: "memory")

// async global->LDS, 16B/lane; LDS dest = wave-uniform base + lane*16
__device__ __forceinline__ void gld_lds16(const ushort* g, ushort* l) {
    __builtin_amdgcn_global_load_lds(
        (const __attribute__((address_space(1))) unsigned int*)g,
        (__attribute__((address_space(3))) unsigned int*)l, 16, 0, 0);
}

// ws layout (ushort elems)
#define WS_XT 0
#define WS_XS 4194304
#define WS_WQ 8388608
#define WS_WK 9437184
#define WS_WV 10485760
#define WS_WO 11534336
#define WS_QH 12582912
#define WS_KH 16777216
#define WS_VT 20971520
#define WS_AO 0   // reuses XT region (XT dead after qkv_gemm)

// ---------------- cast: fp32 -> bf16 into ws ----------------
// seg 2 (Wq) folds the softmax scale log2(e)/sqrt(Dh) into the weights, so
// flash_attn loads Q raw (no per-element repack) and Q is single-rounded.
__global__ __launch_bounds__(256) void cast_bf16(
    const float* __restrict__ s0, const float* __restrict__ s1,
    const float* __restrict__ s2, const float* __restrict__ s3,
    const float* __restrict__ s4, const float* __restrict__ s5,
    ushort* __restrict__ ws)
{
    const int seg = blockIdx.y;
    const float* src = seg == 0 ? s0 : seg == 1 ? s1 : seg == 2 ? s2
                     : seg == 3 ? s3 : seg == 4 ? s4 : s5;
    const size_t off = seg == 0 ? WS_XT : seg == 1 ? WS_XS : seg == 2 ? WS_WQ
                     : seg == 3 ? WS_WK : seg == 4 ? WS_WV : (size_t)WS_WO;
    const int n4 = (seg < 2) ? 1048576 : 262144;  // float4 count
    const float scl = (seg == 2) ? 0.18033688f : 1.0f;
    ushort* d = ws + off;
    for (int i = blockIdx.x * 256 + threadIdx.x; i < n4; i += gridDim.x * 256) {
        float4 f = ((const float4*)src)[i];
        ushort4 u;
        u.x = f2bf(f.x * scl); u.y = f2bf(f.y * scl);
        u.z = f2bf(f.z * scl); u.w = f2bf(f.w * scl);
        ((ushort4*)d)[i] = u;
    }
}

// ---------------- qkv GEMM: 128x128 tile, tri-buffer fine-vmcnt --------------
// grid (8, 32, 3): z = 0:Q, 1:K, 2:Vt. All epilogues route through LDS
// for 16B coalesced stores. XCD swizzle: m-tile = id&31 so all 8 n-tiles of
// an A-panel land on one XCD (id%8 == (id&31)%8; z*256 ≡ 0 mod 8, so modes
// 1/2 sharing xs co-locate too) -> A-panel fetched into one L2, not eight.
// v12 fusion post-mortem: fusing K+Vt (72KB LDS) dropped blocks/CU 3->2 for
// ALL modes and imbalanced block durations -> +8us. Split retained.
__global__ __launch_bounds__(256) void gemm128(
    const ushort* __restrict__ xtb, const ushort* __restrict__ xsb,
    const ushort* __restrict__ wqb, const ushort* __restrict__ wkb,
    const ushort* __restrict__ wvb,
    ushort* __restrict__ qh, ushort* __restrict__ kh, ushort* __restrict__ vt)
{
    __shared__ __align__(16) ushort SM[24576];  // A: 3x4096, B: 12288 + 3x4096

    const int mode = blockIdx.z;
    const ushort* Ap = (mode == 0) ? xtb : xsb;
    const ushort* Wp = (mode == 0) ? wqb : (mode == 1 ? wkb : wvb);

    const int tid  = threadIdx.x;
    const int wave = tid >> 6, lane = tid & 63;
    const int quad = lane >> 4, lidx = lane & 15;
    const int wm = wave >> 1, wn = wave & 1;
    const int id = blockIdx.x + 8 * blockIdx.y;   // 0..255, hw-dispatch linear
    const int m0 = (id & 31) * 128, n0 = (id >> 5) * 128;

    const int slr = lane >> 2, scb = lane & 3;
    auto stage = [&](int k0, int bufi) {
        ushort* Asb = SM + bufi * 4096;
        ushort* Bsb = SM + 12288 + bufi * 4096;
#pragma unroll
        for (int i2 = 0; i2 < 2; ++i2) {
            const int i = wave + i2 * 4;
            const int r = i * 16 + slr;
            gld_lds16(Ap + (size_t)(m0 + r) * 1024 + k0 + scb * 8, Asb + i * 512);
            gld_lds16(Wp + (size_t)(n0 + r) * 1024 + k0 + scb * 8, Bsb + i * 512);
        }
    };

    f32x4 acc[4][4] = {};
    stage(0, 0);
    stage(32, 1);

    for (int kt = 0; kt < 32; ++kt) {
        const int cur = kt % 3;
        WAIT_BARRIER(4);
        stage(((kt + 2) & 31) * 32, (kt + 2) % 3);
        const ushort* Asb = SM + cur * 4096;
        const ushort* Bsb = SM + 12288 + cur * 4096;
        bf16x8 af[4], bfr[4];
#pragma unroll
        for (int i = 0; i < 4; ++i) {
            af[i]  = *(const bf16x8*)(Asb + (wm * 64 + i * 16 + lidx) * 32 + quad * 8);
            bfr[i] = *(const bf16x8*)(Bsb + (wn * 64 + i * 16 + lidx) * 32 + quad * 8);
        }
#pragma unroll
        for (int mi = 0; mi < 4; ++mi)
#pragma unroll
            for (int ni = 0; ni < 4; ++ni)
                acc[mi][ni] = MFMA(af[mi], bfr[ni], acc[mi][ni]);
    }
    __syncthreads();  // full drain once: epilogue reuses SM as scratch

    ushort* scr = SM + wave * 4096;  // wave-private 8 KB (64x64 tile)

    if (mode == 2) {
        // Vt: scr[dl][swz(tl)] then coalesced stores along t
#pragma unroll
        for (int mi = 0; mi < 4; ++mi)
#pragma unroll
            for (int ni = 0; ni < 4; ++ni)
#pragma unroll
                for (int r = 0; r < 4; ++r) {
                    const int dl = ni * 16 + lidx;
                    const int tl = mi * 16 + quad * 4 + r;
                    const int col = (((tl >> 3) ^ (dl & 7)) << 3) | (tl & 7);
                    scr[dl * 64 + col] = f2bf(acc[mi][ni][r]);
                }
        asm volatile("s_waitcnt lgkmcnt(0)" ::: "memory");
        const int hh = (n0 + wn * 64) >> 6;
        const int bb = m0 >> 11;
        const int t0 = (m0 + wm * 64) & 2047;
        ushort* Vtp = vt + (size_t)(bb * 16 + hh) * 64 * 2048;
#pragma unroll
        for (int ii = 0; ii < 8; ++ii) {
            const int dl = ii * 8 + (lane >> 3);
            const int tb = lane & 7;
            uint4 vd = *(const uint4*)(scr + dl * 64 + ((tb ^ (dl & 7)) << 3));
            *(uint4*)(Vtp + (size_t)dl * 2048 + t0 + tb * 8) = vd;
        }
        return;
    }

    // Q/K: scr[tl][swz(dl)] then coalesced 16B stores along d (one head/wave)
#pragma unroll
    for (int mi = 0; mi < 4; ++mi)
#pragma unroll
        for (int ni = 0; ni < 4; ++ni)
#pragma unroll
            for (int r = 0; r < 4; ++r) {
                const int tl = mi * 16 + quad * 4 + r;
                const int dl = ni * 16 + lidx;
                const int col = (((dl >> 3) ^ (tl & 7)) << 3) | (dl & 7);
                scr[tl * 64 + col] = f2bf(acc[mi][ni][r]);
            }
    asm volatile("s_waitcnt lgkmcnt(0)" ::: "memory");
    {
        ushort* dst = (mode == 0) ? qh : kh;
        const int hh = (n0 + wn * 64) >> 6;
        const int bb = m0 >> 11;
        const int tbase = (m0 + wm * 64) & 2047;
        ushort* Hp = dst + (size_t)(bb * 16 + hh) * 2048 * 64;
#pragma unroll
        for (int ii = 0; ii < 8; ++ii) {
            const int tl = ii * 8 + (lane >> 3);
            const int c  = lane & 7;
            uint4 vd = *(const uint4*)(scr + tl * 64 + ((c ^ (tl & 7)) << 3));
            *(uint4*)(Hp + (size_t)(tbase + tl) * 64 + c * 8) = vd;
        }
    }
}

// ---------------- out GEMM v13: 128x128 tile (was 128x64) --------------------
// Same loop as gemm128 mode-0: per-wave 8 ds_read_b128 per 16 MFMA (ratio
// 2.0 vs 1.33 at 128x64), B panel staged once per 128 cols. Grid 256 = 1/CU,
// XCD-swizzled. fp32+bias epilogue stores directly (64B/quad coalesced).
__global__ __launch_bounds__(256) void gemm_out(
    const ushort* __restrict__ aob, const ushort* __restrict__ wob,
    const float* __restrict__ bias, float* __restrict__ outf)
{
    __shared__ __align__(16) ushort SM[24576];  // A: 3x4096, B: 12288 + 3x4096

    const int tid  = threadIdx.x;
    const int wave = tid >> 6, lane = tid & 63;
    const int quad = lane >> 4, lidx = lane & 15;
    const int wm = wave >> 1, wn = wave & 1;
    const int id = blockIdx.x + 8 * blockIdx.y;   // 0..255
    const int m0 = (id & 31) * 128, n0 = (id >> 5) * 128;

    const int slr = lane >> 2, scb = lane & 3;
    auto stage = [&](int k0, int bufi) {
        ushort* Asb = SM + bufi * 4096;
        ushort* Bsb = SM + 12288 + bufi * 4096;
#pragma unroll
        for (int i2 = 0; i2 < 2; ++i2) {
            const int i = wave + i2 * 4;
            const int r = i * 16 + slr;
            gld_lds16(aob + (size_t)(m0 + r) * 1024 + k0 + scb * 8, Asb + i * 512);
            gld_lds16(wob + (size_t)(n0 + r) * 1024 + k0 + scb * 8, Bsb + i * 512);
        }
    };

    f32x4 acc[4][4] = {};
    stage(0, 0);
    stage(32, 1);

    for (int kt = 0; kt < 32; ++kt) {
        const int cur = kt % 3;
        WAIT_BARRIER(4);
        stage(((kt + 2) & 31) * 32, (kt + 2) % 3);
        const ushort* Asb = SM + cur * 4096;
        const ushort* Bsb = SM + 12288 + cur * 4096;
        bf16x8 af[4], bfr[4];
#pragma unroll
        for (int i = 0; i < 4; ++i) {
            af[i]  = *(const bf16x8*)(Asb + (wm * 64 + i * 16 + lidx) * 32 + quad * 8);
            bfr[i] = *(const bf16x8*)(Bsb + (wn * 64 + i * 16 + lidx) * 32 + quad * 8);
        }
#pragma unroll
        for (int mi = 0; mi < 4; ++mi)
#pragma unroll
            for (int ni = 0; ni < 4; ++ni)
                acc[mi][ni] = MFMA(af[mi], bfr[ni], acc[mi][ni]);
    }

    float bv[4];
#pragma unroll
    for (int ni = 0; ni < 4; ++ni)
        bv[ni] = bias[n0 + wn * 64 + ni * 16 + lidx];

#pragma unroll
    for (int mi = 0; mi < 4; ++mi)
#pragma unroll
        for (int ni = 0; ni < 4; ++ni)
#pragma unroll
            for (int r = 0; r < 4; ++r) {
                const int m = m0 + wm * 64 + mi * 16 + quad * 4 + r;
                const int n = n0 + wn * 64 + ni * 16 + lidx;
                outf[(size_t)m * 1024 + n] = acc[mi][ni][r] + bv[ni];
            }
}

// ---------------- flash_attn v10 (proven 51.5us): exact restore -------------
__global__ __launch_bounds__(512, 6) void flash_attn(
    const ushort* __restrict__ Qh, const ushort* __restrict__ Kh,
    const ushort* __restrict__ Vt, ushort* __restrict__ AO)
{
    __shared__ __align__(16) ushort Kb[3][4096];
    __shared__ __align__(16) ushort Vb[3][4096];

    const int tid  = threadIdx.x;
    const int wave = tid >> 6, lane = tid & 63;
    const int quad = lane >> 4, lidx = lane & 15;
    const int bh = blockIdx.y;
    const int b = bh >> 4, h = bh & 15;
    const int qbase = blockIdx.x * 128 + wave * 16;

    const ushort* Qp = Qh + (size_t)bh * 2048 * 64;
    const ushort* Kp = Kh + (size_t)bh * 2048 * 64;
    const ushort* Vp = Vt + (size_t)bh * 64 * 2048;

    // Q as B-operand fragments (pre-scaled at cast): raw 16B loads
    bf16x8 q0, q1;
    {
        const ushort* qr = Qp + (size_t)(qbase + lidx) * 64 + quad * 8;
        q0 = *(const bf16x8*)qr;
        q1 = *(const bf16x8*)(qr + 32);
    }

    // stage 64x64 K tile (row-swizzled) + 64x64 Vt tile (d-swizzled)
    // 512 threads x 16B = 8KB per tile, one issue each
    auto stage = [&](int s0, int bufi) {
        const int slot = wave * 64 + lane;
        const int r  = slot >> 3;
        const int bb = slot & 7;
        const int gb = bb ^ (r & 7);
        gld_lds16(Kp + (size_t)(s0 + r) * 64 + gb * 8, &Kb[bufi][wave * 512]);
        gld_lds16(Vp + (size_t)r * 2048 + s0 + gb * 8, &Vb[bufi][wave * 512]);
    };

    // permlane32_swap then permlane16_swap: (x,y) value-quad layout
    // (x0,x1,x2,x3),(y0,y1,y2,y3) -> (x0,x2,y0,y2),(x1,x3,y1,y3)
    auto swap2 = [&](uint& x, uint& y) {
        uint2v r1 = __builtin_amdgcn_permlane32_swap(x, y, false, false);
        uint2v r2 = __builtin_amdgcn_permlane16_swap(r1[0], r1[1], false, false);
        x = r2[0]; y = r2[1];
    };

    float lsum = 0.f;
    f32x4 o[4] = {};

    stage(0, 0);
    stage(64, 1);

    for (int j = 0; j < 32; ++j) {
        const int cur = j % 3;
        // tile j staged (2 newest stages may still be in flight), sync waves
        WAIT_BARRIER(2);
        stage(((j + 2) & 31) * 64, (j + 2) % 3);

        // QK^T swapped: s[n0][r] = S[q = lidx][k = n0*16 + quad*4 + r]
        f32x4 s[4] = {};
#pragma unroll
        for (int n0 = 0; n0 < 4; ++n0) {
            const int row = n0 * 16 + lidx;
            bf16x8 kA = *(const bf16x8*)&Kb[cur][row * 64 + ((quad ^ (row & 7)) * 8)];
            bf16x8 kB = *(const bf16x8*)&Kb[cur][row * 64 + (((4 + quad) ^ (row & 7)) * 8)];
            s[n0] = MFMA(kA, q0, s[n0]);
            s[n0] = MFMA(kB, q1, s[n0]);
        }

        // hoist V fragment reads: latency hides under the softmax VALU block
        bf16x8 v0[4], v1[4];
#pragma unroll
        for (int n0 = 0; n0 < 4; ++n0) {
            const int d = n0 * 16 + lidx;
            v0[n0] = *(const bf16x8*)&Vb[cur][d * 64 + ((quad ^ (d & 7)) * 8)];
            v1[n0] = *(const bf16x8*)&Vb[cur][d * 64 + (((4 + quad) ^ (d & 7)) * 8)];
        }

        // softmax numerator: exp2 + pack; W[n0][h] = bf16 pair k=(16n0+4q+2h,+1)
        uint W[4][2];
#pragma unroll
        for (int n0 = 0; n0 < 4; ++n0) {
            float p0 = __builtin_amdgcn_exp2f(s[n0][0]);
            float p1 = __builtin_amdgcn_exp2f(s[n0][1]);
            float p2 = __builtin_amdgcn_exp2f(s[n0][2]);
            float p3 = __builtin_amdgcn_exp2f(s[n0][3]);
            lsum += (p0 + p1) + (p2 + p3);
            asm("v_cvt_pk_bf16_f32 %0, %1, %2" : "=v"(W[n0][0]) : "v"(p0), "v"(p1));
            asm("v_cvt_pk_bf16_f32 %0, %1, %2" : "=v"(W[n0][1]) : "v"(p2), "v"(p3));
        }

        // cross-quad redistribution in-register (replaces P LDS round-trip)
        uint aw0 = W[0][0], aw2 = W[1][0]; swap2(aw0, aw2);
        uint aw1 = W[0][1], aw3 = W[1][1]; swap2(aw1, aw3);
        uint bw0 = W[2][0], bw2 = W[3][0]; swap2(bw0, bw2);
        uint bw1 = W[2][1], bw3 = W[3][1]; swap2(bw1, bw3);
        union { uint u[4]; bf16x8 v; } PA, PB;
        PA.u[0] = aw0; PA.u[1] = aw1; PA.u[2] = aw2; PA.u[3] = aw3;
        PB.u[0] = bw0; PB.u[1] = bw1; PB.u[2] = bw2; PB.u[3] = bw3;

#pragma unroll
        for (int n0 = 0; n0 < 4; ++n0) {
            o[n0] = MFMA(PA.v, v0[n0], o[n0]);
            o[n0] = MFMA(PB.v, v1[n0], o[n0]);
        }
        // no end-of-iter barrier: next iter's WAIT_BARRIER(2) provides the
        // sync; tri-buffering guarantees stage(j+2) overwrites a buffer last
        // read at iter j-1 (pre-barrier).
    }

    // row sums: lane owns q = lidx; reduce partial sums over the 4 quads
    {
        float v = lsum;
        v += __shfl_xor(v, 16);
        v += __shfl_xor(v, 32);
        lsum = v;
    }
    float rs[4];
#pragma unroll
    for (int r = 0; r < 4; ++r)
        rs[r] = 1.0f / __shfl(lsum, quad * 4 + r);

#pragma unroll
    for (int n0 = 0; n0 < 4; ++n0)
#pragma unroll
        for (int r = 0; r < 4; ++r) {
            const int tt = qbase + quad * 4 + r;
            const int d  = n0 * 16 + lidx;
            AO[(size_t)(b * 2048 + tt) * 1024 + h * 64 + d] =
                f2bf(o[n0][r] * rs[r]);
        }
}

extern "C" void kernel_launch(void* const* d_in, const int* in_sizes, int n_in,
                              void* d_out, int out_size, void* d_ws, size_t ws_size,
                              hipStream_t stream) {
    const float* xt = (const float*)d_in[0];
    const float* xs = (const float*)d_in[1];
    const float* Wq = (const float*)d_in[2];
    const float* Wk = (const float*)d_in[3];
    const float* Wv = (const float*)d_in[4];
    const float* Wo = (const float*)d_in[5];
    const float* bo = (const float*)d_in[6];
    float* out = (float*)d_out;

    ushort* ws = (ushort*)d_ws;

    cast_bf16<<<dim3(1024, 6, 1), 256, 0, stream>>>(xt, xs, Wq, Wk, Wv, Wo, ws);

    gemm128<<<dim3(8, 32, 3), 256, 0, stream>>>(
        ws + WS_XT, ws + WS_XS, ws + WS_WQ, ws + WS_WK, ws + WS_WV,
        ws + WS_QH, ws + WS_KH, ws + WS_VT);

    flash_attn<<<dim3(16, 32, 1), 512, 0, stream>>>(
        ws + WS_QH, ws + WS_KH, ws + WS_VT, ws + WS_AO);

    gemm_out<<<dim3(8, 32, 1), 256, 0, stream>>>(
        ws + WS_AO, ws + WS_WO, bo, out);
}